// Round 2
// baseline (280.387 us; speedup 1.0000x reference)
//
#include <hip/hip_runtime.h>
#include <hip/hip_bf16.h>

// DomainEncoder fused: 8-expert MoE MLP, N=32768, 256 -> 1024 (LN+ReLU) -> 256.
// Round-2 changes vs round-1 (which was latency-bound: 1 block/CU, 2 waves/SIMD,
// MfmaUtil 8.9%):
//   - RPT 64 -> 32: LDS = 80 KB exactly (Hs 64K + Axs 16K, red aliased in Axs)
//     -> 2 blocks/CU -> 16 waves/CU, cross-block phase overlap.
//   - __launch_bounds__(512,4): force <=128 regs for 4 waves/SIMD.
//   - phase 1 split into 2 column-passes (acc[2][4]=32 regs, B dbuf 32 regs);
//     LN stats accumulate in regs across passes; separate in-LDS normalize pass.
//   - next-pass / next-phase weight preloads issued under preceding compute.
//   - grid 1032 = 8*129 tiles, bijective XCD-chunk swizzle.

#define ND 8
#define NROWS 32768
#define DIN 256
#define DHID 1024
#define DOUT 256
#define RPT 32                // rows per tile
#define MPAD32 33024          // 32768 + 8*32 worst-case padding
#define NT32 1032             // 1024 + 8 worst-case tiles = 8*129

typedef short short8 __attribute__((ext_vector_type(8)));
typedef float floatx4 __attribute__((ext_vector_type(4)));

__device__ __forceinline__ unsigned short f2bf(float f) {
    unsigned u = __builtin_bit_cast(unsigned, f);
    unsigned r = u + 0x7fff + ((u >> 16) & 1);   // RNE (inputs finite)
    return (unsigned short)(r >> 16);
}
__device__ __forceinline__ float bf2f(unsigned short h) {
    unsigned u = ((unsigned)h) << 16;
    return __builtin_bit_cast(float, u);
}

// ---------------- 1. weight transpose fp32[R,C] -> bf16[C,R], per-domain z ----
__global__ void transpose_bf16(const float* __restrict__ in,
                               unsigned short* __restrict__ out,
                               int R, int C) {
    __shared__ float t[32][33];
    const int z = blockIdx.z;
    const int c0 = blockIdx.x * 32, r0 = blockIdx.y * 32;
    const int tx = threadIdx.x & 31, ty = threadIdx.x >> 5;   // 32x8
    const float* src = in + (size_t)z * R * C;
    unsigned short* dst = out + (size_t)z * R * C;
#pragma unroll
    for (int i = 0; i < 32; i += 8)
        t[ty + i][tx] = src[(size_t)(r0 + ty + i) * C + c0 + tx];
    __syncthreads();
#pragma unroll
    for (int i = 0; i < 32; i += 8)
        dst[(size_t)(c0 + ty + i) * R + r0 + tx] = f2bf(t[tx][ty + i]);
}

// ---------------- 2a. init perm/counters ------------------------------------
__global__ void zero_init(int* __restrict__ perm, int* __restrict__ cnt) {
    int i = blockIdx.x * 256 + threadIdx.x;
    if (i < MPAD32) perm[i] = -1;
    if (i < 16) cnt[i] = 0;            // counts[8] + cursors[8]
}

// ---------------- 2b. histogram (block-aggregated atomics) --------------------
__global__ void histo(const int* __restrict__ dt, int* __restrict__ counts) {
    __shared__ int lc[ND];
    if (threadIdx.x < ND) lc[threadIdx.x] = 0;
    __syncthreads();
    int i = blockIdx.x * 256 + threadIdx.x;      // grid covers exactly NROWS
    atomicAdd(&lc[dt[i]], 1);
    __syncthreads();
    if (threadIdx.x < ND) atomicAdd(&counts[threadIdx.x], lc[threadIdx.x]);
}

// ---------------- 2c. 32-aligned offsets + tile metadata ---------------------
__global__ void make_meta(const int* __restrict__ counts, int* __restrict__ cursors,
                          int2* __restrict__ meta) {
    __shared__ int base[ND], ntc[ND];
    const int t = threadIdx.x;     // 64 threads
    if (t == 0) {
        int off = 0;
        for (int d = 0; d < ND; d++) {
            base[d] = off;
            ntc[d] = (counts[d] + 31) >> 5;
            cursors[d] = off;
            off += ntc[d] << 5;
        }
    }
    __syncthreads();
    for (int i = t; i < NT32; i += 64) {
        int2 m = make_int2(-1, 0);
#pragma unroll
        for (int d = 0; d < ND; d++) {
            const int ti = i - (base[d] >> 5);
            if (ti >= 0 && ti < ntc[d]) m = make_int2(d, base[d] + (ti << 5));
        }
        meta[i] = m;
    }
}

// ---------------- 2d. position assignment: 8 global atomics per 256 rows ------
__global__ __launch_bounds__(256)
void assign_pos(const int* __restrict__ dt, int* __restrict__ cursors,
                int* __restrict__ perm) {
    __shared__ int lcnt[ND];
    __shared__ int lbase[ND];
    const int tid = threadIdx.x;
    if (tid < ND) lcnt[tid] = 0;
    __syncthreads();
    const int r = blockIdx.x * 256 + tid;
    const int d = dt[r];
    const int myrank = atomicAdd(&lcnt[d], 1);   // LDS atomic: cheap
    __syncthreads();
    if (tid < ND && lcnt[tid] > 0)
        lbase[tid] = atomicAdd(&cursors[tid], lcnt[tid]);  // 8 global atomics/block
    __syncthreads();
    perm[lbase[d] + myrank] = r;
}

// ---------------- 3. fused MLP: one 32-row single-domain tile per block -------
__global__ __launch_bounds__(512, 4)
void fused_mlp(const float* __restrict__ x,
               const unsigned short* __restrict__ W1T,   // [8][1024][256] bf16
               const float* __restrict__ b1,             // [8][1024]
               const float* __restrict__ gamma,
               const float* __restrict__ beta,
               const unsigned short* __restrict__ W2T,   // [8][256][1024] bf16
               const float* __restrict__ b2,             // [8][256]
               const int2* __restrict__ meta,
               const int* __restrict__ perm,
               float* __restrict__ out) {
    // XCD-chunked bijective swizzle: 1032 = 8 * 129
    const int bid = (int)blockIdx.x;
    const int swz = (bid & 7) * (NT32 >> 3) + (bid >> 3);
    const int2 md = meta[swz];
    const int dom = md.x;
    if (dom < 0) return;
    const int m0 = md.y;

    __shared__ __attribute__((aligned(16))) unsigned short Hs[RPT * DHID];  // 64 KB
    __shared__ __attribute__((aligned(16))) unsigned short Axs[RPT * DIN];  // 16 KB
    float* red = (float*)Axs;   // aliased AFTER all Axs reads are done:
                                // [0..255] s, [256..511] s2, [512..543] mu, [544..575] rstd

    const int tid = threadIdx.x;
    const int lane = tid & 63;
    const int w = tid >> 6;          // wave 0..7
    const int l15 = lane & 15;
    const int q = lane >> 4;         // 0..3

    const unsigned short* W1d = W1T + (size_t)dom * DHID * DIN;
    const unsigned short* Bp0 = W1d + (size_t)(w * 64 + l15) * DIN + q * 8;

    // preload pass-0 B fragments (in flight during gather)
    short8 bA[4], bB[4];
#pragma unroll
    for (int j = 0; j < 4; ++j)
        bA[j] = *(const short8*)(Bp0 + (size_t)j * 16 * DIN);

    // ---- phase 0: gather x rows fp32 -> bf16 into Axs (swizzled) ----
    {
        const int row = tid >> 4;                  // 32 rows, 16 threads each
        const int c16 = tid & 15;
        const int orig = perm[m0 + row];
        const int sw = (row & 7) << 3;             // short-index XOR (16B slots)
        if (orig >= 0) {
            const float4* src = (const float4*)(x + (size_t)orig * DIN);
#pragma unroll
            for (int it = 0; it < 4; ++it) {
                const int c = it * 16 + c16;       // float4 chunk 0..63
                const float4 v = src[c];
                ushort4 o;
                o.x = f2bf(v.x); o.y = f2bf(v.y); o.z = f2bf(v.z); o.w = f2bf(v.w);
                *(ushort4*)&Axs[(row * DIN + c * 4) ^ sw] = o;
            }
        } else {
            const ushort4 z = {0, 0, 0, 0};
#pragma unroll
            for (int it = 0; it < 4; ++it) {
                const int c = it * 16 + c16;
                *(ushort4*)&Axs[(row * DIN + c * 4) ^ sw] = z;
            }
        }
    }
    __syncthreads();                               // Axs ready

    // ---- phase 1: h = x @ W1^T in 2 column-passes; wave w owns 64 cols/pass ----
    float sp[2][4], sp2[2][4];                     // per-lane row partials (8 rows)
#pragma unroll
    for (int i = 0; i < 2; ++i)
#pragma unroll
        for (int r = 0; r < 4; ++r) { sp[i][r] = 0.f; sp2[i][r] = 0.f; }

#pragma unroll
    for (int p = 0; p < 2; ++p) {
        const int cb = p * 512 + w * 64;           // wave's col base this pass
        const unsigned short* B1p = Bp0 + (size_t)(p * 512) * DIN;

        floatx4 acc[2][4];
#pragma unroll
        for (int i = 0; i < 2; ++i)
#pragma unroll
            for (int j = 0; j < 4; ++j) acc[i][j] = 0.f;

#pragma unroll
        for (int t = 0; t < 8; ++t) {              // K = 256, step 32
            const int k0 = t * 32;
            short8* bc = (t & 1) ? bB : bA;        // static under full unroll
            short8* bn = (t & 1) ? bA : bB;
            if (t < 7) {
#pragma unroll
                for (int j = 0; j < 4; ++j)
                    bn[j] = *(const short8*)(B1p + (size_t)j * 16 * DIN + (k0 + 32));
            } else if (p == 0) {                   // prefetch pass-1 k0=0 into bA
#pragma unroll
                for (int j = 0; j < 4; ++j)
                    bA[j] = *(const short8*)(Bp0 + (size_t)(512 + j * 16) * DIN);
            }
            short8 a[2];
#pragma unroll
            for (int i = 0; i < 2; ++i) {
                const int row = i * 16 + l15;
                a[i] = *(const short8*)&Axs[(row * DIN + k0 + q * 8) ^ ((row & 7) << 3)];
            }
            __builtin_amdgcn_s_setprio(1);
#pragma unroll
            for (int i = 0; i < 2; ++i)
#pragma unroll
                for (int j = 0; j < 4; ++j)
                    acc[i][j] = __builtin_amdgcn_mfma_f32_16x16x32_bf16(a[i], bc[j], acc[i][j], 0, 0, 0);
            __builtin_amdgcn_s_setprio(0);
        }

        // + b1, accumulate LN stats (fp32), write h' bf16 to Hs
#pragma unroll
        for (int j = 0; j < 4; ++j) {
            const float b1v = b1[dom * DHID + cb + j * 16 + l15];
#pragma unroll
            for (int i = 0; i < 2; ++i)
#pragma unroll
                for (int r = 0; r < 4; ++r) acc[i][j][r] += b1v;
        }
#pragma unroll
        for (int i = 0; i < 2; ++i)
#pragma unroll
            for (int r = 0; r < 4; ++r) {
                float s = 0.f, s2 = 0.f;
#pragma unroll
                for (int j = 0; j < 4; ++j) {
                    const float v = acc[i][j][r];
                    s += v; s2 += v * v;
                }
                sp[i][r] += s; sp2[i][r] += s2;
            }
        // C/D layout: col = lane&15, row = (lane>>4)*4 + reg  [m89-verified]
#pragma unroll
        for (int i = 0; i < 2; ++i)
#pragma unroll
            for (int r = 0; r < 4; ++r) {
                const int row = i * 16 + q * 4 + r;
                const int sw = (row & 7) << 3;
#pragma unroll
                for (int j = 0; j < 4; ++j)
                    Hs[(row * DHID + cb + j * 16 + l15) ^ sw] = f2bf(acc[i][j][r]);
            }
    }

    __syncthreads();     // ALL waves done reading Axs -> red may alias it now

    // 16-lane butterfly: row totals over this wave's 128 cols
#pragma unroll
    for (int i = 0; i < 2; ++i)
#pragma unroll
        for (int r = 0; r < 4; ++r) {
#pragma unroll
            for (int o = 8; o; o >>= 1) {
                sp[i][r]  += __shfl_xor(sp[i][r], o, 64);
                sp2[i][r] += __shfl_xor(sp2[i][r], o, 64);
            }
            if (l15 == 0) {
                const int row = i * 16 + q * 4 + r;
                red[w * 32 + row]       = sp[i][r];
                red[256 + w * 32 + row] = sp2[i][r];
            }
        }

    // preload phase-2 B fragments (in flight through reduce + normalize)
    const int c0w = w * 32;
    const unsigned short* B2p = W2T + (size_t)dom * DOUT * DHID
                              + (size_t)(c0w + l15) * DHID + q * 8;
    short8 cA[2], cB[2];
#pragma unroll
    for (int jj = 0; jj < 2; ++jj)
        cA[jj] = *(const short8*)(B2p + (size_t)jj * 16 * DHID);

    __syncthreads();
    if (tid < 32) {                                 // cross-wave reduce -> mu/rstd
        float s = 0.f, s2 = 0.f;
#pragma unroll
        for (int ww = 0; ww < 8; ++ww) {
            s  += red[ww * 32 + tid];
            s2 += red[256 + ww * 32 + tid];
        }
        const float mu  = s * (1.f / 1024.f);
        const float var = fmaxf(s2 * (1.f / 1024.f) - mu * mu, 0.f);
        red[512 + tid] = mu;
        red[544 + tid] = rsqrtf(var + 1e-5f);
    }
    __syncthreads();

    // ---- normalize + ReLU pass over Hs (in place) ----
    {
        const float* gdp = gamma + dom * DHID;
        const float* bdp = beta + dom * DHID;
#pragma unroll
        for (int kq = 0; kq < 8; ++kq) {
            const int ch = tid + kq * 512;          // 16B chunk 0..4095
            const int row = ch >> 7;
            const int c0 = (ch & 127) * 8;
            const int idx = (row * DHID + c0) ^ ((row & 7) << 3);
            short8 hv = *(short8*)&Hs[idx];
            const float mu   = red[512 + row];
            const float rstd = red[544 + row];
            const float4 g0 = *(const float4*)(gdp + c0);
            const float4 g1 = *(const float4*)(gdp + c0 + 4);
            const float4 be0 = *(const float4*)(bdp + c0);
            const float4 be1 = *(const float4*)(bdp + c0 + 4);
            short8 o;
            o[0] = (short)f2bf(fmaxf((bf2f((unsigned short)hv[0]) - mu) * rstd * g0.x + be0.x, 0.f));
            o[1] = (short)f2bf(fmaxf((bf2f((unsigned short)hv[1]) - mu) * rstd * g0.y + be0.y, 0.f));
            o[2] = (short)f2bf(fmaxf((bf2f((unsigned short)hv[2]) - mu) * rstd * g0.z + be0.z, 0.f));
            o[3] = (short)f2bf(fmaxf((bf2f((unsigned short)hv[3]) - mu) * rstd * g0.w + be0.w, 0.f));
            o[4] = (short)f2bf(fmaxf((bf2f((unsigned short)hv[4]) - mu) * rstd * g1.x + be1.x, 0.f));
            o[5] = (short)f2bf(fmaxf((bf2f((unsigned short)hv[5]) - mu) * rstd * g1.y + be1.y, 0.f));
            o[6] = (short)f2bf(fmaxf((bf2f((unsigned short)hv[6]) - mu) * rstd * g1.z + be1.z, 0.f));
            o[7] = (short)f2bf(fmaxf((bf2f((unsigned short)hv[7]) - mu) * rstd * g1.w + be1.w, 0.f));
            *(short8*)&Hs[idx] = o;
        }
    }
    __syncthreads();                                // Hs normalized, ready

    // ---- phase 2: out = Hs @ W2^T, wave w owns cols [w*32, w*32+32) ----
    floatx4 acc2[2][2];
#pragma unroll
    for (int ii = 0; ii < 2; ++ii) { acc2[ii][0] = 0.f; acc2[ii][1] = 0.f; }

    for (int t = 0; t < 32; t += 2) {               // K = 1024, step 32, 2-step body
        const int k0 = t * 32;
        if (t + 1 < 32) {
#pragma unroll
            for (int jj = 0; jj < 2; ++jj)
                cB[jj] = *(const short8*)(B2p + (size_t)jj * 16 * DHID + (k0 + 32));
        }
        {
            short8 a[2];
#pragma unroll
            for (int ii = 0; ii < 2; ++ii) {
                const int row = ii * 16 + l15;
                a[ii] = *(const short8*)&Hs[(row * DHID + k0 + q * 8) ^ ((row & 7) << 3)];
            }
            __builtin_amdgcn_s_setprio(1);
#pragma unroll
            for (int ii = 0; ii < 2; ++ii)
#pragma unroll
                for (int jj = 0; jj < 2; ++jj)
                    acc2[ii][jj] = __builtin_amdgcn_mfma_f32_16x16x32_bf16(a[ii], cA[jj], acc2[ii][jj], 0, 0, 0);
            __builtin_amdgcn_s_setprio(0);
        }
        if (t + 2 < 32) {
#pragma unroll
            for (int jj = 0; jj < 2; ++jj)
                cA[jj] = *(const short8*)(B2p + (size_t)jj * 16 * DHID + (k0 + 64));
        }
        {
            short8 a[2];
#pragma unroll
            for (int ii = 0; ii < 2; ++ii) {
                const int row = ii * 16 + l15;
                a[ii] = *(const short8*)&Hs[(row * DHID + k0 + 32 + q * 8) ^ ((row & 7) << 3)];
            }
            __builtin_amdgcn_s_setprio(1);
#pragma unroll
            for (int ii = 0; ii < 2; ++ii)
#pragma unroll
                for (int jj = 0; jj < 2; ++jj)
                    acc2[ii][jj] = __builtin_amdgcn_mfma_f32_16x16x32_bf16(a[ii], cB[jj], acc2[ii][jj], 0, 0, 0);
            __builtin_amdgcn_s_setprio(0);
        }
    }

    // ---- epilogue: scatter out = acc2 + b2 via perm (padding rows skipped) ----
    float b2v[2];
#pragma unroll
    for (int jj = 0; jj < 2; ++jj)
        b2v[jj] = b2[dom * DOUT + c0w + jj * 16 + l15];
#pragma unroll
    for (int ii = 0; ii < 2; ++ii)
#pragma unroll
        for (int r = 0; r < 4; ++r) {
            const int row = ii * 16 + q * 4 + r;
            const int orig = perm[m0 + row];
            if (orig < 0) continue;
#pragma unroll
            for (int jj = 0; jj < 2; ++jj)
                out[(size_t)orig * DOUT + c0w + jj * 16 + l15] = acc2[ii][jj][r] + b2v[jj];
        }
}

// ---------------- launch ------------------------------------------------------
extern "C" void kernel_launch(void* const* d_in, const int* in_sizes, int n_in,
                              void* d_out, int out_size, void* d_ws, size_t ws_size,
                              hipStream_t stream) {
    const float* x = (const float*)d_in[0];
    const int* dt = (const int*)d_in[1];
    const float* W1 = (const float*)d_in[2];
    const float* b1 = (const float*)d_in[3];
    const float* gamma = (const float*)d_in[4];
    const float* beta = (const float*)d_in[5];
    const float* W2 = (const float*)d_in[6];
    const float* b2 = (const float*)d_in[7];
    float* out = (float*)d_out;

    char* ws = (char*)d_ws;
    size_t off = 0;
    auto take = [&](size_t nbytes) -> char* {
        char* p = ws + off;
        off = (off + nbytes + 255) & ~(size_t)255;
        return p;
    };
    unsigned short* W1T = (unsigned short*)take((size_t)ND * DHID * DIN * 2);   // [8,1024,256]
    unsigned short* W2T = (unsigned short*)take((size_t)ND * DOUT * DHID * 2);  // [8,256,1024]
    int* PERM = (int*)take(MPAD32 * 4);
    int* CNT  = (int*)take(64);            // counts[8] then cursors[8]
    int2* META = (int2*)take(NT32 * 8);
    (void)ws_size; (void)n_in; (void)in_sizes; (void)out_size;

    int* COUNTS = CNT;
    int* CURSORS = CNT + 8;

    transpose_bf16<<<dim3(DHID / 32, DIN / 32, ND), 256, 0, stream>>>(W1, W1T, DIN, DHID);
    transpose_bf16<<<dim3(DOUT / 32, DHID / 32, ND), 256, 0, stream>>>(W2, W2T, DHID, DOUT);
    zero_init<<<(MPAD32 + 255) / 256, 256, 0, stream>>>(PERM, CNT);
    histo<<<NROWS / 256, 256, 0, stream>>>(dt, COUNTS);
    make_meta<<<1, 64, 0, stream>>>(COUNTS, CURSORS, META);
    assign_pos<<<NROWS / 256, 256, 0, stream>>>(dt, CURSORS, PERM);
    fused_mlp<<<NT32, 512, 0, stream>>>(x, W1T, b1, gamma, beta, W2T, b2, META, PERM, out);
}

// Round 3
// 221.823 us; speedup vs baseline: 1.2640x; 1.2640x over previous
//
#include <hip/hip_runtime.h>
#include <hip/hip_bf16.h>

// DomainEncoder: 8-expert MoE MLP, N=32768, 256 -> 1024 (LN+ReLU) -> 256.
// Round-3: back to the proven round-0 split pipeline (fused rounds 1/2 were
// latency/spill-bound regressions), with two surgical fusions:
//   - GEMM-A epilogue computes per-row LN partial sums (s, s2) over its 128
//     cols -> SPART[8][MPAD] (per-n-block partials, no global atomics).
//   - ln_relu kernel REMOVED: GEMM-B's A-staging is reg-staged (global->reg
//     -> LN+ReLU in fp32 -> ds_write_b128, same LDS layout) using mu/rstd
//     folded from SPART in the prologue. B-staging keeps global_load_lds.
// Saves the 138 MB H round-trip (~20 us) at the cost of staging VALU.

#define ND 8
#define NROWS 32768
#define DIN 256
#define DHID 1024
#define DOUT 256
#define MPAD 33792          // 32768 + 8*128 worst-case padding
#define NTILES 264          // 256 + 8 worst-case row tiles

typedef short short8 __attribute__((ext_vector_type(8)));
typedef float floatx4 __attribute__((ext_vector_type(4)));

__device__ __forceinline__ unsigned short f2bf(float f) {
    unsigned u = __builtin_bit_cast(unsigned, f);
    unsigned r = u + 0x7fff + ((u >> 16) & 1);   // RNE (inputs finite)
    return (unsigned short)(r >> 16);
}
__device__ __forceinline__ float bf2f(unsigned short h) {
    unsigned u = ((unsigned)h) << 16;
    return __builtin_bit_cast(float, u);
}

#define GLDS16(gp, lp) __builtin_amdgcn_global_load_lds( \
    (const __attribute__((address_space(1))) void*)(gp), \
    (__attribute__((address_space(3))) void*)(lp), 16, 0, 0)

// ---------------- 1. weight transpose fp32[R,C] -> bf16[C,R], per-domain z ----
__global__ void transpose_bf16(const float* __restrict__ in,
                               unsigned short* __restrict__ out,
                               int R, int C) {
    __shared__ float t[32][33];
    const int z = blockIdx.z;
    const int c0 = blockIdx.x * 32, r0 = blockIdx.y * 32;
    const int tx = threadIdx.x & 31, ty = threadIdx.x >> 5;   // 32x8
    const float* src = in + (size_t)z * R * C;
    unsigned short* dst = out + (size_t)z * R * C;
#pragma unroll
    for (int i = 0; i < 32; i += 8)
        t[ty + i][tx] = src[(size_t)(r0 + ty + i) * C + c0 + tx];
    __syncthreads();
#pragma unroll
    for (int i = 0; i < 32; i += 8)
        dst[(size_t)(c0 + ty + i) * R + r0 + tx] = f2bf(t[tx][ty + i]);
}

// ---------------- 2a. init perm/counters -------------------------------------
__global__ void zero_init(int* __restrict__ perm, int* __restrict__ cnt) {
    int i = blockIdx.x * 256 + threadIdx.x;
    if (i < MPAD) perm[i] = -1;
    if (i < 16) cnt[i] = 0;            // counts[8] + cursors[8]
}

// ---------------- 2b. histogram (block-aggregated atomics) --------------------
__global__ void histo(const int* __restrict__ dt, int* __restrict__ counts) {
    __shared__ int lc[ND];
    if (threadIdx.x < ND) lc[threadIdx.x] = 0;
    __syncthreads();
    int i = blockIdx.x * 256 + threadIdx.x;      // grid covers exactly NROWS
    atomicAdd(&lc[dt[i]], 1);
    __syncthreads();
    if (threadIdx.x < ND) atomicAdd(&counts[threadIdx.x], lc[threadIdx.x]);
}

// ---------------- 2c. aligned offsets + tile metadata (single thread) ---------
__global__ void make_meta(const int* __restrict__ counts, int* __restrict__ cursors,
                          int2* __restrict__ meta) {
    if (threadIdx.x == 0 && blockIdx.x == 0) {
        int off = 0, t = 0;
        for (int d = 0; d < ND; d++) {
            cursors[d] = off;
            int nt = (counts[d] + 127) >> 7;
            for (int i = 0; i < nt; i++) meta[t++] = make_int2(d, off + (i << 7));
            off += nt << 7;
        }
        for (; t < NTILES; t++) meta[t] = make_int2(-1, 0);
    }
}

// ---------------- 2d. position assignment: 8 global atomics per 256 rows ------
__global__ __launch_bounds__(256)
void assign_pos(const int* __restrict__ dt, int* __restrict__ cursors,
                int* __restrict__ perm, int* __restrict__ pos) {
    __shared__ int lcnt[ND];
    __shared__ int lbase[ND];
    const int tid = threadIdx.x;
    if (tid < ND) lcnt[tid] = 0;
    __syncthreads();
    const int r = blockIdx.x * 256 + tid;
    const int d = dt[r];
    const int myrank = atomicAdd(&lcnt[d], 1);   // LDS atomic: cheap
    __syncthreads();
    if (tid < ND && lcnt[tid] > 0)
        lbase[tid] = atomicAdd(&cursors[tid], lcnt[tid]);  // 8 global atomics/block
    __syncthreads();
    const int p = lbase[d] + myrank;
    pos[r] = p;
    perm[p] = r;
}

// ---------------- 2e. gather copy: one wave per row, coalesced ---------------
__global__ __launch_bounds__(256)
void copy_rows(const float* __restrict__ x, const int* __restrict__ pos,
               unsigned short* __restrict__ xs) {
    const int tid = threadIdx.x;
    const int lane = tid & 63;
    const int r = blockIdx.x * 4 + (tid >> 6);           // 4 rows per block
    const int p = pos[r];
    float4 v = ((const float4*)(x + (size_t)r * DIN))[lane];   // 16B/lane read
    ushort4 o;
    o.x = f2bf(v.x); o.y = f2bf(v.y); o.z = f2bf(v.z); o.w = f2bf(v.w);
    ((ushort4*)(xs + (size_t)p * DIN))[lane] = o;              // 8B/lane write
}

// ---------------- 3/5. grouped GEMM, m97 structure ---------------------------
// C[128x128] per block, 4 waves in 2x2, each wave 64x64 = 4x4 mfma_16x16x32_bf16.
// A: [MPAD,K] bf16 row-major (sorted rows). Bt: [ND,Ntot,K] bf16 (B^T).
// ISB=false (GEMM-A): epilogue writes bf16 H=h+b1 and per-row LN partials.
// ISB=true  (GEMM-B): A-staging applies LN+ReLU from SPART; scatter fp32 out.
template <int K, bool ISB>
__global__ __launch_bounds__(256, 2)
void gemm_bt(const unsigned short* __restrict__ A,
             const unsigned short* __restrict__ Bt,
             const float* __restrict__ bias,
             const int2* __restrict__ meta,
             const int* __restrict__ perm,
             unsigned short* __restrict__ Cbf,
             float* __restrict__ Cf,
             const int Ntot,
             float2* __restrict__ spart,          // A: out [8][MPAD]; B: in
             const float* __restrict__ gamma,     // B only
             const float* __restrict__ beta) {    // B only
    const int2 md = meta[blockIdx.x];
    const int dom = md.x;
    if (dom < 0) return;
    const int m0 = md.y;
    const int n0 = blockIdx.y * 128;

    __shared__ unsigned short As[128 * 32];   // [m][k], 8 KB
    __shared__ unsigned short Bs[128 * 32];   // [n][k], 8 KB
    __shared__ float sred[2][128];            // A only: per-row s, s2

    const int tid = threadIdx.x;
    const int lane = tid & 63;
    const int w = tid >> 6;            // wave id 0..3
    const int wr = w >> 1, wc = w & 1; // 2x2 wave grid

    const unsigned short* Abase = A + (size_t)m0 * K;
    const unsigned short* Bbase = Bt + (size_t)dom * Ntot * K + (size_t)n0 * K;

    if (!ISB) {
        if (tid < 128) { sred[0][tid] = 0.f; sred[1][tid] = 0.f; }
    }

    // B-path: per-thread fixed rows for the LN-staged A tile.
    // chunk c = w*128 + it*64 + lane -> m = c>>2 (= w*32 + (lane>>2) + it*16),
    // kc = lane&3 (same for both its). mu/rstd per row from SPART (8 partials).
    const int ma = (w * 128 + lane) >> 2;
    const int kc = lane & 3;
    float muv[2], rsv[2];
    if (ISB) {
#pragma unroll
        for (int h2 = 0; h2 < 2; ++h2) {
            const int rm = m0 + ma + h2 * 16;
            float s = 0.f, s2 = 0.f;
#pragma unroll
            for (int nb = 0; nb < 8; ++nb) {
                const float2 p = spart[(size_t)nb * MPAD + rm];
                s += p.x; s2 += p.y;
            }
            const float mu = s * (1.f / 1024.f);
            const float var = fmaxf(s2 * (1.f / 1024.f) - mu * mu, 0.f);
            muv[h2] = mu;
            rsv[h2] = rsqrtf(var + 1e-5f);
        }
    }

    floatx4 acc[4][4];
#pragma unroll
    for (int i = 0; i < 4; i++)
#pragma unroll
        for (int j = 0; j < 4; j++) acc[i][j] = 0.f;

    for (int k0 = 0; k0 < K; k0 += 32) {
        if (!ISB) {
            // stage A via global_load_lds (raw bf16)
#pragma unroll
            for (int it = 0; it < 2; ++it) {
                const int c = w * 128 + it * 64 + lane;
                const int m = c >> 2, kcc = c & 3;
                GLDS16(Abase + (size_t)m * K + k0 + kcc * 8, &As[(w * 128 + it * 64) * 8]);
            }
        } else {
            // stage A via registers with LN+ReLU transform
            const float* gp = gamma + dom * DHID + k0 + kc * 8;
            const float* bp = beta + dom * DHID + k0 + kc * 8;
            const float4 g0 = ((const float4*)gp)[0];
            const float4 g1 = ((const float4*)gp)[1];
            const float4 e0 = ((const float4*)bp)[0];
            const float4 e1 = ((const float4*)bp)[1];
#pragma unroll
            for (int h2 = 0; h2 < 2; ++h2) {
                const int m = ma + h2 * 16;
                const short8 hv = *(const short8*)(Abase + (size_t)m * K + k0 + kc * 8);
                const float mu = muv[h2], rs = rsv[h2];
                short8 o;
                o[0] = (short)f2bf(fmaxf((bf2f((unsigned short)hv[0]) - mu) * rs * g0.x + e0.x, 0.f));
                o[1] = (short)f2bf(fmaxf((bf2f((unsigned short)hv[1]) - mu) * rs * g0.y + e0.y, 0.f));
                o[2] = (short)f2bf(fmaxf((bf2f((unsigned short)hv[2]) - mu) * rs * g0.z + e0.z, 0.f));
                o[3] = (short)f2bf(fmaxf((bf2f((unsigned short)hv[3]) - mu) * rs * g0.w + e0.w, 0.f));
                o[4] = (short)f2bf(fmaxf((bf2f((unsigned short)hv[4]) - mu) * rs * g1.x + e1.x, 0.f));
                o[5] = (short)f2bf(fmaxf((bf2f((unsigned short)hv[5]) - mu) * rs * g1.y + e1.y, 0.f));
                o[6] = (short)f2bf(fmaxf((bf2f((unsigned short)hv[6]) - mu) * rs * g1.z + e1.z, 0.f));
                o[7] = (short)f2bf(fmaxf((bf2f((unsigned short)hv[7]) - mu) * rs * g1.w + e1.w, 0.f));
                *(short8*)&As[(w * 128 + h2 * 64 + lane) * 8] = o;
            }
        }
        // stage B via global_load_lds (both variants)
#pragma unroll
        for (int it = 0; it < 2; ++it) {
            const int c = w * 128 + it * 64 + lane;
            const int m = c >> 2, kcc = c & 3;
            GLDS16(Bbase + (size_t)m * K + k0 + kcc * 8, &Bs[(w * 128 + it * 64) * 8]);
        }
        __syncthreads();   // drains vmcnt + lgkmcnt before barrier

        short8 a[4], b[4];
        const int kk = (lane >> 4) * 8;
#pragma unroll
        for (int i = 0; i < 4; i++) {
            const int m = wr * 64 + i * 16 + (lane & 15);
            a[i] = *(const short8*)&As[m * 32 + kk];
            const int n = wc * 64 + i * 16 + (lane & 15);
            b[i] = *(const short8*)&Bs[n * 32 + kk];
        }
#pragma unroll
        for (int i = 0; i < 4; i++)
#pragma unroll
            for (int j = 0; j < 4; j++)
                acc[i][j] = __builtin_amdgcn_mfma_f32_16x16x32_bf16(a[i], b[j], acc[i][j], 0, 0, 0);
        __syncthreads();
    }

    // epilogue: C/D layout col=lane&15, row=(lane>>4)*4+reg  [m89-verified]
    const int quad = lane >> 4;
    const int l15 = lane & 15;
    if (!ISB) {
        float bv[4];
#pragma unroll
        for (int j = 0; j < 4; j++)
            bv[j] = bias[dom * Ntot + n0 + wc * 64 + j * 16 + l15];
#pragma unroll
        for (int i = 0; i < 4; i++) {
#pragma unroll
            for (int r = 0; r < 4; r++) {
                const int rl = wr * 64 + i * 16 + quad * 4 + r;
                float s = 0.f, s2 = 0.f;
#pragma unroll
                for (int j = 0; j < 4; j++) {
                    const float v = acc[i][j][r] + bv[j];
                    Cbf[(size_t)(m0 + rl) * Ntot + n0 + wc * 64 + j * 16 + l15] = f2bf(v);
                    s += v; s2 += v * v;
                }
#pragma unroll
                for (int o = 8; o; o >>= 1) {
                    s  += __shfl_xor(s, o, 64);
                    s2 += __shfl_xor(s2, o, 64);
                }
                if (l15 == 0) {
                    atomicAdd(&sred[0][rl], s);    // LDS atomics: cheap
                    atomicAdd(&sred[1][rl], s2);
                }
            }
        }
        __syncthreads();
        if (tid < 128)
            spart[(size_t)blockIdx.y * MPAD + m0 + tid] =
                make_float2(sred[0][tid], sred[1][tid]);
    } else {
#pragma unroll
        for (int i = 0; i < 4; i++) {
            const int rowbase = m0 + wr * 64 + i * 16 + quad * 4;
#pragma unroll
            for (int r = 0; r < 4; r++) {
                const int orig = perm[rowbase + r];
                if (orig < 0) continue;     // padding row
#pragma unroll
                for (int j = 0; j < 4; j++) {
                    const int col = n0 + wc * 64 + j * 16 + l15;
                    Cf[(size_t)orig * Ntot + col] = acc[i][j][r] + bias[dom * Ntot + col];
                }
            }
        }
    }
}

// ---------------- launch ------------------------------------------------------
extern "C" void kernel_launch(void* const* d_in, const int* in_sizes, int n_in,
                              void* d_out, int out_size, void* d_ws, size_t ws_size,
                              hipStream_t stream) {
    const float* x = (const float*)d_in[0];
    const int* dt = (const int*)d_in[1];
    const float* W1 = (const float*)d_in[2];
    const float* b1 = (const float*)d_in[3];
    const float* gamma = (const float*)d_in[4];
    const float* beta = (const float*)d_in[5];
    const float* W2 = (const float*)d_in[6];
    const float* b2 = (const float*)d_in[7];
    float* out = (float*)d_out;

    char* ws = (char*)d_ws;
    size_t off = 0;
    auto take = [&](size_t nbytes) -> char* {
        char* p = ws + off;
        off = (off + nbytes + 255) & ~(size_t)255;
        return p;
    };
    unsigned short* W1T = (unsigned short*)take((size_t)ND * DHID * DIN * 2);   // [8,1024,256]
    unsigned short* W2T = (unsigned short*)take((size_t)ND * DOUT * DHID * 2);  // [8,256,1024]
    unsigned short* XS  = (unsigned short*)take((size_t)MPAD * DIN * 2);
    unsigned short* H   = (unsigned short*)take((size_t)MPAD * DHID * 2);
    float2* SPART = (float2*)take((size_t)8 * MPAD * 8);   // [8][MPAD] (s,s2)
    int* PERM   = (int*)take(MPAD * 4);
    int* POS    = (int*)take(NROWS * 4);
    int* CNT    = (int*)take(64);            // counts[8] then cursors[8]
    int2* META  = (int2*)take(NTILES * 8);
    (void)ws_size; (void)n_in; (void)in_sizes; (void)out_size;

    int* COUNTS = CNT;
    int* CURSORS = CNT + 8;

    transpose_bf16<<<dim3(DHID / 32, DIN / 32, ND), 256, 0, stream>>>(W1, W1T, DIN, DHID);
    transpose_bf16<<<dim3(DOUT / 32, DHID / 32, ND), 256, 0, stream>>>(W2, W2T, DHID, DOUT);
    zero_init<<<(MPAD + 255) / 256, 256, 0, stream>>>(PERM, CNT);
    histo<<<NROWS / 256, 256, 0, stream>>>(dt, COUNTS);
    make_meta<<<1, 1, 0, stream>>>(COUNTS, CURSORS, META);
    assign_pos<<<NROWS / 256, 256, 0, stream>>>(dt, CURSORS, PERM, POS);
    copy_rows<<<NROWS / 4, 256, 0, stream>>>(x, POS, XS);
    gemm_bt<DIN, false><<<dim3(NTILES, DHID / 128), 256, 0, stream>>>(
        XS, W1T, b1, META, nullptr, H, nullptr, DHID, SPART, nullptr, nullptr);
    gemm_bt<DHID, true><<<dim3(NTILES, DOUT / 128), 256, 0, stream>>>(
        H, W2T, b2, META, PERM, nullptr, out, DOUT, SPART, gamma, beta);
}

// Round 4
// 212.932 us; speedup vs baseline: 1.3168x; 1.0418x over previous
//
#include <hip/hip_runtime.h>
#include <hip/hip_bf16.h>

// DomainEncoder: 8-expert MoE MLP, N=32768, 256 -> 1024 (LN+ReLU) -> 256.
// Round-4 vs round-3 (221.8 us):
//   - GEMM-B A-staging software-pipelined (T14): next-step H + gamma/beta
//     loads issued right after barrier#1, in flight under ds_read+MFMA,
//     drained by barrier#2's vmcnt(0); transform consumes registers only.
//     GLDS B issued before the transform. Transform folded to fma form.
//   - dispatch count 10 -> 7: transposes merged (one flattened grid, also
//     zeroes CNT), zero_init+histo merged, make_meta parallelized (64 thr).

#define ND 8
#define NROWS 32768
#define DIN 256
#define DHID 1024
#define DOUT 256
#define MPAD 33792          // 32768 + 8*128 worst-case padding
#define NTILES 264          // 256 + 8 worst-case row tiles

typedef short short8 __attribute__((ext_vector_type(8)));
typedef float floatx4 __attribute__((ext_vector_type(4)));

__device__ __forceinline__ unsigned short f2bf(float f) {
    unsigned u = __builtin_bit_cast(unsigned, f);
    unsigned r = u + 0x7fff + ((u >> 16) & 1);   // RNE (inputs finite)
    return (unsigned short)(r >> 16);
}
__device__ __forceinline__ float bf2f(unsigned short h) {
    unsigned u = ((unsigned)h) << 16;
    return __builtin_bit_cast(float, u);
}

#define GLDS16(gp, lp) __builtin_amdgcn_global_load_lds( \
    (const __attribute__((address_space(1))) void*)(gp), \
    (__attribute__((address_space(3))) void*)(lp), 16, 0, 0)

// ---------------- 1. both weight transposes in one dispatch -------------------
// W1: fp32[8][256][1024] -> bf16[8][1024][256]   (2048 blocks)
// W2: fp32[8][1024][256] -> bf16[8][256][1024]   (2048 blocks)
// Also zeroes CNT (stream-serialized before init_histo).
__global__ void transpose_both(const float* __restrict__ W1, unsigned short* __restrict__ W1T,
                               const float* __restrict__ W2, unsigned short* __restrict__ W2T,
                               int* __restrict__ cnt) {
    if (blockIdx.x == 0 && threadIdx.x < 16) cnt[threadIdx.x] = 0;
    __shared__ float t[32][33];
    int b = blockIdx.x;
    const float* in; unsigned short* out; int R, C, bx, by, z;
    if (b < 2048) {           // W1: R=DIN, C=DHID, grid (32, 8, 8)
        in = W1; out = W1T; R = DIN; C = DHID;
        bx = b & 31; by = (b >> 5) & 7; z = b >> 8;
    } else {                  // W2: R=DHID, C=DOUT, grid (8, 32, 8)
        b -= 2048;
        in = W2; out = W2T; R = DHID; C = DOUT;
        bx = b & 7; by = (b >> 3) & 31; z = b >> 8;
    }
    const int c0 = bx * 32, r0 = by * 32;
    const int tx = threadIdx.x & 31, ty = threadIdx.x >> 5;   // 32x8
    const float* src = in + (size_t)z * R * C;
    unsigned short* dst = out + (size_t)z * R * C;
#pragma unroll
    for (int i = 0; i < 32; i += 8)
        t[ty + i][tx] = src[(size_t)(r0 + ty + i) * C + c0 + tx];
    __syncthreads();
#pragma unroll
    for (int i = 0; i < 32; i += 8)
        dst[(size_t)(c0 + ty + i) * R + r0 + tx] = f2bf(t[tx][ty + i]);
}

// ---------------- 2a. perm init + histogram (merged) --------------------------
__global__ void init_histo(const int* __restrict__ dt, int* __restrict__ perm,
                           int* __restrict__ counts) {
    const int i = blockIdx.x * 256 + threadIdx.x;   // grid covers MPAD
    if (i < MPAD) perm[i] = -1;
    __shared__ int lc[ND];
    if (threadIdx.x < ND) lc[threadIdx.x] = 0;
    __syncthreads();
    if (i < NROWS) atomicAdd(&lc[dt[i]], 1);
    __syncthreads();
    if (threadIdx.x < ND && lc[threadIdx.x] > 0)
        atomicAdd(&counts[threadIdx.x], lc[threadIdx.x]);
}

// ---------------- 2b. aligned offsets + tile metadata (64 threads) ------------
__global__ void make_meta(const int* __restrict__ counts, int* __restrict__ cursors,
                          int2* __restrict__ meta) {
    __shared__ int base[ND], ntc[ND];
    const int t = threadIdx.x;
    if (t == 0) {
        int off = 0;
        for (int d = 0; d < ND; d++) {
            base[d] = off;
            ntc[d] = (counts[d] + 127) >> 7;
            cursors[d] = off;
            off += ntc[d] << 7;
        }
    }
    __syncthreads();
    for (int i = t; i < NTILES; i += 64) {
        int2 m = make_int2(-1, 0);
#pragma unroll
        for (int d = 0; d < ND; d++) {
            const int ti = i - (base[d] >> 7);
            if (ti >= 0 && ti < ntc[d]) m = make_int2(d, base[d] + (ti << 7));
        }
        meta[i] = m;
    }
}

// ---------------- 2c. position assignment: 8 global atomics per 256 rows ------
__global__ __launch_bounds__(256)
void assign_pos(const int* __restrict__ dt, int* __restrict__ cursors,
                int* __restrict__ perm, int* __restrict__ pos) {
    __shared__ int lcnt[ND];
    __shared__ int lbase[ND];
    const int tid = threadIdx.x;
    if (tid < ND) lcnt[tid] = 0;
    __syncthreads();
    const int r = blockIdx.x * 256 + tid;
    const int d = dt[r];
    const int myrank = atomicAdd(&lcnt[d], 1);   // LDS atomic: cheap
    __syncthreads();
    if (tid < ND && lcnt[tid] > 0)
        lbase[tid] = atomicAdd(&cursors[tid], lcnt[tid]);  // 8 global atomics/block
    __syncthreads();
    const int p = lbase[d] + myrank;
    pos[r] = p;
    perm[p] = r;
}

// ---------------- 2d. gather copy: one wave per row, coalesced ---------------
__global__ __launch_bounds__(256)
void copy_rows(const float* __restrict__ x, const int* __restrict__ pos,
               unsigned short* __restrict__ xs) {
    const int tid = threadIdx.x;
    const int lane = tid & 63;
    const int r = blockIdx.x * 4 + (tid >> 6);           // 4 rows per block
    const int p = pos[r];
    float4 v = ((const float4*)(x + (size_t)r * DIN))[lane];   // 16B/lane read
    ushort4 o;
    o.x = f2bf(v.x); o.y = f2bf(v.y); o.z = f2bf(v.z); o.w = f2bf(v.w);
    ((ushort4*)(xs + (size_t)p * DIN))[lane] = o;              // 8B/lane write
}

// ---------------- 3/5. grouped GEMM, m97 structure ---------------------------
// C[128x128] per block, 4 waves in 2x2, each wave 64x64 = 4x4 mfma_16x16x32_bf16.
// ISB=false (GEMM-A): epilogue writes bf16 H=h+b1 and per-row LN partials.
// ISB=true  (GEMM-B): A-staging applies LN+ReLU from SPART with software-
//                     pipelined register prefetch; scatter fp32 out via perm.
template <int K, bool ISB>
__global__ __launch_bounds__(256, 2)
void gemm_bt(const unsigned short* __restrict__ A,
             const unsigned short* __restrict__ Bt,
             const float* __restrict__ bias,
             const int2* __restrict__ meta,
             const int* __restrict__ perm,
             unsigned short* __restrict__ Cbf,
             float* __restrict__ Cf,
             const int Ntot,
             float2* __restrict__ spart,          // A: out [8][MPAD]; B: in
             const float* __restrict__ gamma,     // B only
             const float* __restrict__ beta) {    // B only
    const int2 md = meta[blockIdx.x];
    const int dom = md.x;
    if (dom < 0) return;
    const int m0 = md.y;
    const int n0 = blockIdx.y * 128;

    __shared__ unsigned short As[128 * 32];   // [m][k], 8 KB
    __shared__ unsigned short Bs[128 * 32];   // [n][k], 8 KB
    __shared__ float sred[2][128];            // A only: per-row s, s2 (DCE'd in B)

    const int tid = threadIdx.x;
    const int lane = tid & 63;
    const int w = tid >> 6;            // wave id 0..3
    const int wr = w >> 1, wc = w & 1; // 2x2 wave grid

    const unsigned short* Abase = A + (size_t)m0 * K;
    const unsigned short* Bbase = Bt + (size_t)dom * Ntot * K + (size_t)n0 * K;

    if (!ISB) {
        if (tid < 128) { sred[0][tid] = 0.f; sred[1][tid] = 0.f; }
    }

    // B-path: per-thread fixed rows ma, ma+16 with fixed kc across the K-loop.
    const int ma = (w * 128 + lane) >> 2;
    const int kc = lane & 3;
    float muv[2], rsv[2];
    short8 hv0{}, hv1{};
    float4 gc0{}, gc1{}, ec0{}, ec1{};
    if (ISB) {
#pragma unroll
        for (int h2 = 0; h2 < 2; ++h2) {
            const int rm = m0 + ma + h2 * 16;
            float s = 0.f, s2 = 0.f;
#pragma unroll
            for (int nb = 0; nb < 8; ++nb) {
                const float2 p = spart[(size_t)nb * MPAD + rm];
                s += p.x; s2 += p.y;
            }
            const float mu = s * (1.f / 1024.f);
            const float var = fmaxf(s2 * (1.f / 1024.f) - mu * mu, 0.f);
            muv[h2] = mu;
            rsv[h2] = rsqrtf(var + 1e-5f);
        }
        // prologue: load k0=0 operands into registers
        const float* gp = gamma + dom * DHID + kc * 8;
        const float* bp = beta + dom * DHID + kc * 8;
        gc0 = ((const float4*)gp)[0]; gc1 = ((const float4*)gp)[1];
        ec0 = ((const float4*)bp)[0]; ec1 = ((const float4*)bp)[1];
        hv0 = *(const short8*)(Abase + (size_t)ma * K + kc * 8);
        hv1 = *(const short8*)(Abase + (size_t)(ma + 16) * K + kc * 8);
    }

    floatx4 acc[4][4];
#pragma unroll
    for (int i = 0; i < 4; i++)
#pragma unroll
        for (int j = 0; j < 4; j++) acc[i][j] = 0.f;

    for (int k0 = 0; k0 < K; k0 += 32) {
        // stage B first: fire-and-forget, starts L2 fetch under the transform
#pragma unroll
        for (int it = 0; it < 2; ++it) {
            const int c = w * 128 + it * 64 + lane;
            const int m = c >> 2, kcc = c & 3;
            GLDS16(Bbase + (size_t)m * K + k0 + kcc * 8, &Bs[(w * 128 + it * 64) * 8]);
        }
        if (!ISB) {
#pragma unroll
            for (int it = 0; it < 2; ++it) {
                const int c = w * 128 + it * 64 + lane;
                const int m = c >> 2, kcc = c & 3;
                GLDS16(Abase + (size_t)m * K + k0 + kcc * 8, &As[(w * 128 + it * 64) * 8]);
            }
        } else {
            // transform register-resident H(k0) -> As  (no loads on this path)
            const float gA[8] = {gc0.x, gc0.y, gc0.z, gc0.w, gc1.x, gc1.y, gc1.z, gc1.w};
            const float eA[8] = {ec0.x, ec0.y, ec0.z, ec0.w, ec1.x, ec1.y, ec1.z, ec1.w};
#pragma unroll
            for (int h2 = 0; h2 < 2; ++h2) {
                const float mu = muv[h2], rs = rsv[h2];
                const short8 hvv = h2 ? hv1 : hv0;
                short8 o;
#pragma unroll
                for (int e = 0; e < 8; ++e) {
                    const float rg = gA[e] * rs;
                    const float v = fmaxf(fmaf(bf2f((unsigned short)hvv[e]), rg,
                                               fmaf(-mu, rg, eA[e])), 0.f);
                    o[e] = (short)f2bf(v);
                }
                *(short8*)&As[(w * 128 + h2 * 64 + lane) * 8] = o;
            }
        }
        __syncthreads();   // #1: staging complete (vmcnt+lgkm drained)

        // T14 prefetch: issue NEXT step's A-operand loads now; they fly under
        // ds_read+MFMA and are guaranteed complete by barrier #2's vmcnt(0).
        short8 nh0{}, nh1{};
        float4 ng0{}, ng1{}, ne0{}, ne1{};
        const bool more = ISB && (k0 + 32 < K);
        if (more) {
            const float* gp = gamma + dom * DHID + k0 + 32 + kc * 8;
            const float* bp = beta + dom * DHID + k0 + 32 + kc * 8;
            ng0 = ((const float4*)gp)[0]; ng1 = ((const float4*)gp)[1];
            ne0 = ((const float4*)bp)[0]; ne1 = ((const float4*)bp)[1];
            nh0 = *(const short8*)(Abase + (size_t)ma * K + k0 + 32 + kc * 8);
            nh1 = *(const short8*)(Abase + (size_t)(ma + 16) * K + k0 + 32 + kc * 8);
        }

        short8 a[4], b[4];
        const int kk = (lane >> 4) * 8;
#pragma unroll
        for (int i = 0; i < 4; i++) {
            const int m = wr * 64 + i * 16 + (lane & 15);
            a[i] = *(const short8*)&As[m * 32 + kk];
            const int n = wc * 64 + i * 16 + (lane & 15);
            b[i] = *(const short8*)&Bs[n * 32 + kk];
        }
#pragma unroll
        for (int i = 0; i < 4; i++)
#pragma unroll
            for (int j = 0; j < 4; j++)
                acc[i][j] = __builtin_amdgcn_mfma_f32_16x16x32_bf16(a[i], b[j], acc[i][j], 0, 0, 0);
        __syncthreads();   // #2: LDS reusable; prefetch loads drained

        if (more) { hv0 = nh0; hv1 = nh1; gc0 = ng0; gc1 = ng1; ec0 = ne0; ec1 = ne1; }
    }

    // epilogue: C/D layout col=lane&15, row=(lane>>4)*4+reg  [m89-verified]
    const int quad = lane >> 4;
    const int l15 = lane & 15;
    if (!ISB) {
        float bv[4];
#pragma unroll
        for (int j = 0; j < 4; j++)
            bv[j] = bias[dom * Ntot + n0 + wc * 64 + j * 16 + l15];
#pragma unroll
        for (int i = 0; i < 4; i++) {
#pragma unroll
            for (int r = 0; r < 4; r++) {
                const int rl = wr * 64 + i * 16 + quad * 4 + r;
                float s = 0.f, s2 = 0.f;
#pragma unroll
                for (int j = 0; j < 4; j++) {
                    const float v = acc[i][j][r] + bv[j];
                    Cbf[(size_t)(m0 + rl) * Ntot + n0 + wc * 64 + j * 16 + l15] = f2bf(v);
                    s += v; s2 += v * v;
                }
#pragma unroll
                for (int o = 8; o; o >>= 1) {
                    s  += __shfl_xor(s, o, 64);
                    s2 += __shfl_xor(s2, o, 64);
                }
                if (l15 == 0) {
                    atomicAdd(&sred[0][rl], s);    // LDS atomics: cheap
                    atomicAdd(&sred[1][rl], s2);
                }
            }
        }
        __syncthreads();
        if (tid < 128)
            spart[(size_t)blockIdx.y * MPAD + m0 + tid] =
                make_float2(sred[0][tid], sred[1][tid]);
    } else {
#pragma unroll
        for (int i = 0; i < 4; i++) {
            const int rowbase = m0 + wr * 64 + i * 16 + quad * 4;
#pragma unroll
            for (int r = 0; r < 4; r++) {
                const int orig = perm[rowbase + r];
                if (orig < 0) continue;     // padding row
#pragma unroll
                for (int j = 0; j < 4; j++) {
                    const int col = n0 + wc * 64 + j * 16 + l15;
                    Cf[(size_t)orig * Ntot + col] = acc[i][j][r] + bias[dom * Ntot + col];
                }
            }
        }
    }
}

// ---------------- launch ------------------------------------------------------
extern "C" void kernel_launch(void* const* d_in, const int* in_sizes, int n_in,
                              void* d_out, int out_size, void* d_ws, size_t ws_size,
                              hipStream_t stream) {
    const float* x = (const float*)d_in[0];
    const int* dt = (const int*)d_in[1];
    const float* W1 = (const float*)d_in[2];
    const float* b1 = (const float*)d_in[3];
    const float* gamma = (const float*)d_in[4];
    const float* beta = (const float*)d_in[5];
    const float* W2 = (const float*)d_in[6];
    const float* b2 = (const float*)d_in[7];
    float* out = (float*)d_out;

    char* ws = (char*)d_ws;
    size_t off = 0;
    auto take = [&](size_t nbytes) -> char* {
        char* p = ws + off;
        off = (off + nbytes + 255) & ~(size_t)255;
        return p;
    };
    unsigned short* W1T = (unsigned short*)take((size_t)ND * DHID * DIN * 2);   // [8,1024,256]
    unsigned short* W2T = (unsigned short*)take((size_t)ND * DOUT * DHID * 2);  // [8,256,1024]
    unsigned short* XS  = (unsigned short*)take((size_t)MPAD * DIN * 2);
    unsigned short* H   = (unsigned short*)take((size_t)MPAD * DHID * 2);
    float2* SPART = (float2*)take((size_t)8 * MPAD * 8);   // [8][MPAD] (s,s2)
    int* PERM   = (int*)take(MPAD * 4);
    int* POS    = (int*)take(NROWS * 4);
    int* CNT    = (int*)take(64);            // counts[8] then cursors[8]
    int2* META  = (int2*)take(NTILES * 8);
    (void)ws_size; (void)n_in; (void)in_sizes; (void)out_size;

    int* COUNTS = CNT;
    int* CURSORS = CNT + 8;

    transpose_both<<<4096, 256, 0, stream>>>(W1, W1T, W2, W2T, CNT);
    init_histo<<<MPAD / 256, 256, 0, stream>>>(dt, PERM, COUNTS);
    make_meta<<<1, 64, 0, stream>>>(COUNTS, CURSORS, META);
    assign_pos<<<NROWS / 256, 256, 0, stream>>>(dt, CURSORS, PERM, POS);
    copy_rows<<<NROWS / 4, 256, 0, stream>>>(x, POS, XS);
    gemm_bt<DIN, false><<<dim3(NTILES, DHID / 128), 256, 0, stream>>>(
        XS, W1T, b1, META, nullptr, H, nullptr, DHID, SPART, nullptr, nullptr);
    gemm_bt<DHID, true><<<dim3(NTILES, DOUT / 128), 256, 0, stream>>>(
        H, W2T, b2, META, PERM, nullptr, out, DOUT, SPART, gamma, beta);
}

// Round 5
// 201.576 us; speedup vs baseline: 1.3910x; 1.0563x over previous
//
#include <hip/hip_runtime.h>
#include <hip/hip_bf16.h>

// DomainEncoder: 8-expert MoE MLP, N=32768, 256 -> 1024 (LN+ReLU) -> 256.
// Round-5 vs round-4 (212.9 us; gemmB 58 us = 4.3K cyc/K-step, ~2.7K of it
// exposed memory latency from vmcnt(0)-draining TWO barriers per step):
//   - Both GEMMs: T3-minimum pipeline. Double-buffered LDS; stage tile t+1
//     into buf^1 FIRST, then ds_read+MFMA tile t from buf, then ONE
//     __syncthreads. Stage flight window = full compute phase.
//   - gemmB: gamma/beta staged to LDS in prologue (no per-step global loads);
//     H prefetched 1 tile ahead into regs; LN transform before the barrier.
//   - T1 XCD-chunked swizzle + n-block folding: {same tile, different n0}
//     are consecutive work-ids -> same XCD -> shared A-rows L2-hit.
//   - gemmA LDS 33 KB -> 4 blocks/CU.

#define ND 8
#define NROWS 32768
#define DIN 256
#define DHID 1024
#define DOUT 256
#define MPAD 33792          // 32768 + 8*128 worst-case padding
#define NTILES 264          // 256 + 8 worst-case row tiles (264 = 8*33)

typedef short short8 __attribute__((ext_vector_type(8)));
typedef float floatx4 __attribute__((ext_vector_type(4)));

__device__ __forceinline__ unsigned short f2bf(float f) {
    unsigned u = __builtin_bit_cast(unsigned, f);
    unsigned r = u + 0x7fff + ((u >> 16) & 1);   // RNE (inputs finite)
    return (unsigned short)(r >> 16);
}
__device__ __forceinline__ float bf2f(unsigned short h) {
    unsigned u = ((unsigned)h) << 16;
    return __builtin_bit_cast(float, u);
}

#define GLDS16(gp, lp) __builtin_amdgcn_global_load_lds( \
    (const __attribute__((address_space(1))) void*)(gp), \
    (__attribute__((address_space(3))) void*)(lp), 16, 0, 0)

// ---------------- 1. both weight transposes in one dispatch -------------------
__global__ void transpose_both(const float* __restrict__ W1, unsigned short* __restrict__ W1T,
                               const float* __restrict__ W2, unsigned short* __restrict__ W2T,
                               int* __restrict__ cnt) {
    if (blockIdx.x == 0 && threadIdx.x < 16) cnt[threadIdx.x] = 0;
    __shared__ float t[32][33];
    int b = blockIdx.x;
    const float* in; unsigned short* out; int R, C, bx, by, z;
    if (b < 2048) {           // W1: R=DIN, C=DHID
        in = W1; out = W1T; R = DIN; C = DHID;
        bx = b & 31; by = (b >> 5) & 7; z = b >> 8;
    } else {                  // W2: R=DHID, C=DOUT
        b -= 2048;
        in = W2; out = W2T; R = DHID; C = DOUT;
        bx = b & 7; by = (b >> 3) & 31; z = b >> 8;
    }
    const int c0 = bx * 32, r0 = by * 32;
    const int tx = threadIdx.x & 31, ty = threadIdx.x >> 5;   // 32x8
    const float* src = in + (size_t)z * R * C;
    unsigned short* dst = out + (size_t)z * R * C;
#pragma unroll
    for (int i = 0; i < 32; i += 8)
        t[ty + i][tx] = src[(size_t)(r0 + ty + i) * C + c0 + tx];
    __syncthreads();
#pragma unroll
    for (int i = 0; i < 32; i += 8)
        dst[(size_t)(c0 + ty + i) * R + r0 + tx] = f2bf(t[tx][ty + i]);
}

// ---------------- 2a. perm init + histogram (merged) --------------------------
__global__ void init_histo(const int* __restrict__ dt, int* __restrict__ perm,
                           int* __restrict__ counts) {
    const int i = blockIdx.x * 256 + threadIdx.x;   // grid covers MPAD
    if (i < MPAD) perm[i] = -1;
    __shared__ int lc[ND];
    if (threadIdx.x < ND) lc[threadIdx.x] = 0;
    __syncthreads();
    if (i < NROWS) atomicAdd(&lc[dt[i]], 1);
    __syncthreads();
    if (threadIdx.x < ND && lc[threadIdx.x] > 0)
        atomicAdd(&counts[threadIdx.x], lc[threadIdx.x]);
}

// ---------------- 2b. aligned offsets + tile metadata (64 threads) ------------
__global__ void make_meta(const int* __restrict__ counts, int* __restrict__ cursors,
                          int2* __restrict__ meta) {
    __shared__ int base[ND], ntc[ND];
    const int t = threadIdx.x;
    if (t == 0) {
        int off = 0;
        for (int d = 0; d < ND; d++) {
            base[d] = off;
            ntc[d] = (counts[d] + 127) >> 7;
            cursors[d] = off;
            off += ntc[d] << 7;
        }
    }
    __syncthreads();
    for (int i = t; i < NTILES; i += 64) {
        int2 m = make_int2(-1, 0);
#pragma unroll
        for (int d = 0; d < ND; d++) {
            const int ti = i - (base[d] >> 7);
            if (ti >= 0 && ti < ntc[d]) m = make_int2(d, base[d] + (ti << 7));
        }
        meta[i] = m;
    }
}

// ---------------- 2c. position assignment: 8 global atomics per 256 rows ------
__global__ __launch_bounds__(256)
void assign_pos(const int* __restrict__ dt, int* __restrict__ cursors,
                int* __restrict__ perm, int* __restrict__ pos) {
    __shared__ int lcnt[ND];
    __shared__ int lbase[ND];
    const int tid = threadIdx.x;
    if (tid < ND) lcnt[tid] = 0;
    __syncthreads();
    const int r = blockIdx.x * 256 + tid;
    const int d = dt[r];
    const int myrank = atomicAdd(&lcnt[d], 1);   // LDS atomic: cheap
    __syncthreads();
    if (tid < ND && lcnt[tid] > 0)
        lbase[tid] = atomicAdd(&cursors[tid], lcnt[tid]);  // 8 global atomics/block
    __syncthreads();
    const int p = lbase[d] + myrank;
    pos[r] = p;
    perm[p] = r;
}

// ---------------- 2d. gather copy: one wave per row, coalesced ---------------
__global__ __launch_bounds__(256)
void copy_rows(const float* __restrict__ x, const int* __restrict__ pos,
               unsigned short* __restrict__ xs) {
    const int tid = threadIdx.x;
    const int lane = tid & 63;
    const int r = blockIdx.x * 4 + (tid >> 6);           // 4 rows per block
    const int p = pos[r];
    float4 v = ((const float4*)(x + (size_t)r * DIN))[lane];   // 16B/lane read
    ushort4 o;
    o.x = f2bf(v.x); o.y = f2bf(v.y); o.z = f2bf(v.z); o.w = f2bf(v.w);
    ((ushort4*)(xs + (size_t)p * DIN))[lane] = o;              // 8B/lane write
}

// ---------------- 3/5. grouped GEMM, dbuf single-barrier pipeline -------------
// C[128x128] per block, 4 waves 2x2, each wave 64x64 = 4x4 mfma_16x16x32_bf16.
// ISB=false (GEMM-A): A,B staged via global_load_lds; epilogue writes H=h+b1
//                     bf16 + per-row LN partials to SPART.
// ISB=true  (GEMM-B): B via global_load_lds; A reg-staged with LN+ReLU
//                     transform (mu/rstd from SPART, gamma/beta from LDS).
template <int K, bool ISB>
__global__ __launch_bounds__(256, 2)
void gemm_bt(const unsigned short* __restrict__ A,
             const unsigned short* __restrict__ Bt,
             const float* __restrict__ bias,
             const int2* __restrict__ meta,
             const int* __restrict__ perm,
             unsigned short* __restrict__ Cbf,
             float* __restrict__ Cf,
             const int Ntot,
             float2* __restrict__ spart,
             const float* __restrict__ gamma,
             const float* __restrict__ beta) {
    constexpr int NB = ISB ? 2 : 8;          // n-blocks per tile
    constexpr int NWG = NTILES * NB;         // 528 / 2112 (both %8==0)
    constexpr int NS = K / 32;               // K-steps: 32 / 8
    // T1 XCD-chunked swizzle; consecutive work-ids (same tile, diff n0) share an XCD
    const int bid = (int)blockIdx.x;
    const int wid = (bid & 7) * (NWG >> 3) + (bid >> 3);
    const int tile = wid / NB;
    const int n0 = (wid % NB) * 128;
    const int2 md = meta[tile];
    const int dom = md.x;
    if (dom < 0) return;
    const int m0 = md.y;

    __shared__ unsigned short As[2][128 * 32];   // 2 x 8 KB
    __shared__ unsigned short Bs[2][128 * 32];   // 2 x 8 KB
    __shared__ float gb[ISB ? 2048 : 64];        // B: gamma[1024] beta[1024]
    __shared__ float sred[2][128];               // A: per-row s, s2

    const int tid = threadIdx.x;
    const int lane = tid & 63;
    const int w = tid >> 6;            // wave id 0..3
    const int wr = w >> 1, wc = w & 1; // 2x2 wave grid
    const int l15 = lane & 15;

    const unsigned short* Abase = A + (size_t)m0 * K;
    const unsigned short* Bbase = Bt + (size_t)dom * Ntot * K + (size_t)n0 * K;

    if (!ISB) {
        if (tid < 128) { sred[0][tid] = 0.f; sred[1][tid] = 0.f; }
    }

    // ---- B-path prologue: gamma/beta -> LDS, mu/rstd from SPART, H(0)/H(1) regs
    const int ma = (w * 128 + lane) >> 2;    // this thread's staged row (and +16)
    const int kc = lane & 3;                 // fixed 16B k-chunk within 32
    float muv[2], rsv[2];
    short8 hv0{}, hv1{};
    if (ISB) {
        ((float4*)gb)[tid] = ((const float4*)(gamma + dom * DHID))[tid];
        ((float4*)(gb + 1024))[tid] = ((const float4*)(beta + dom * DHID))[tid];
#pragma unroll
        for (int h2 = 0; h2 < 2; ++h2) {
            const int rm = m0 + ma + h2 * 16;
            float s = 0.f, s2 = 0.f;
#pragma unroll
            for (int nb = 0; nb < 8; ++nb) {
                const float2 p = spart[(size_t)nb * MPAD + rm];
                s += p.x; s2 += p.y;
            }
            const float mu = s * (1.f / 1024.f);
            const float var = fmaxf(s2 * (1.f / 1024.f) - mu * mu, 0.f);
            muv[h2] = mu;
            rsv[h2] = rsqrtf(var + 1e-5f);
        }
        hv0 = *(const short8*)(Abase + (size_t)ma * K + kc * 8);
        hv1 = *(const short8*)(Abase + (size_t)(ma + 16) * K + kc * 8);
    }

    // staging helpers (macros keep GLDS dest wave-uniform)
#define STAGE_B(buf, t_) {                                                     \
        const int k0_ = (t_) * 32;                                             \
        _Pragma("unroll")                                                      \
        for (int it = 0; it < 2; ++it) {                                       \
            const int c = w * 128 + it * 64 + lane;                            \
            const int m_ = c >> 2, kcc = c & 3;                                \
            GLDS16(Bbase + (size_t)m_ * K + k0_ + kcc * 8,                     \
                   &Bs[buf][(w * 128 + it * 64) * 8]);                         \
        }                                                                      \
    }
#define STAGE_A_GLDS(buf, t_) {                                                \
        const int k0_ = (t_) * 32;                                             \
        _Pragma("unroll")                                                      \
        for (int it = 0; it < 2; ++it) {                                       \
            const int c = w * 128 + it * 64 + lane;                            \
            const int m_ = c >> 2, kcc = c & 3;                                \
            GLDS16(Abase + (size_t)m_ * K + k0_ + kcc * 8,                     \
                   &As[buf][(w * 128 + it * 64) * 8]);                         \
        }                                                                      \
    }
#define STAGE_A_XFRM(buf, t_) {                                                \
        const int k1 = (t_) * 32 + kc * 8;                                     \
        const float4 g0 = *(const float4*)&gb[k1];                             \
        const float4 g1 = *(const float4*)&gb[k1 + 4];                         \
        const float4 e0 = *(const float4*)&gb[1024 + k1];                      \
        const float4 e1 = *(const float4*)&gb[1024 + k1 + 4];                  \
        const float gA[8] = {g0.x, g0.y, g0.z, g0.w, g1.x, g1.y, g1.z, g1.w};  \
        const float eA[8] = {e0.x, e0.y, e0.z, e0.w, e1.x, e1.y, e1.z, e1.w};  \
        _Pragma("unroll")                                                      \
        for (int h2 = 0; h2 < 2; ++h2) {                                       \
            const float mu = muv[h2], rs = rsv[h2];                            \
            const short8 hvv = h2 ? hv1 : hv0;                                 \
            short8 o;                                                          \
            _Pragma("unroll")                                                  \
            for (int e = 0; e < 8; ++e) {                                      \
                const float rg = gA[e] * rs;                                   \
                const float v = fmaxf(fmaf(bf2f((unsigned short)hvv[e]), rg,   \
                                           fmaf(-mu, rg, eA[e])), 0.f);        \
                o[e] = (short)f2bf(v);                                         \
            }                                                                  \
            *(short8*)&As[buf][(w * 128 + h2 * 64 + lane) * 8] = o;            \
        }                                                                      \
    }
#define LOAD_H(t_) {                                                           \
        const int k0_ = (t_) * 32;                                             \
        hv0 = *(const short8*)(Abase + (size_t)ma * K + k0_ + kc * 8);         \
        hv1 = *(const short8*)(Abase + (size_t)(ma + 16) * K + k0_ + kc * 8);  \
    }

    floatx4 acc[4][4];
#pragma unroll
    for (int i = 0; i < 4; i++)
#pragma unroll
        for (int j = 0; j < 4; j++) acc[i][j] = 0.f;

    // ---- prologue: stage tile 0 into buf 0 ----
    STAGE_B(0, 0)
    if (!ISB) {
        STAGE_A_GLDS(0, 0)
    } else {
        STAGE_A_XFRM(0, 0)     // uses H(0) regs (auto-waited)
        LOAD_H(1)
    }
    __syncthreads();

    // ---- main loop: one barrier per K-step ----
    int cur = 0;
    const int kk = (lane >> 4) * 8;
    for (int t = 0; t < NS - 1; ++t) {
        const int nx = cur ^ 1;
        // stage tile t+1 FIRST (flies under ds_read + MFMA below)
        STAGE_B(nx, t + 1)
        if (!ISB) {
            STAGE_A_GLDS(nx, t + 1)
        } else {
            STAGE_A_XFRM(nx, t + 1)   // uses H(t+1)
            if (t + 2 < NS) LOAD_H(t + 2)
        }
        // compute tile t
        short8 a[4], b[4];
#pragma unroll
        for (int i = 0; i < 4; i++) {
            const int m = wr * 64 + i * 16 + l15;
            a[i] = *(const short8*)&As[cur][m * 32 + kk];
            const int n = wc * 64 + i * 16 + l15;
            b[i] = *(const short8*)&Bs[cur][n * 32 + kk];
        }
        __builtin_amdgcn_s_setprio(1);
#pragma unroll
        for (int i = 0; i < 4; i++)
#pragma unroll
            for (int j = 0; j < 4; j++)
                acc[i][j] = __builtin_amdgcn_mfma_f32_16x16x32_bf16(a[i], b[j], acc[i][j], 0, 0, 0);
        __builtin_amdgcn_s_setprio(0);
        __syncthreads();     // drains stage(t+1); next iter reads buf nx
        cur = nx;
    }
    // last tile (no staging)
    {
        short8 a[4], b[4];
#pragma unroll
        for (int i = 0; i < 4; i++) {
            const int m = wr * 64 + i * 16 + l15;
            a[i] = *(const short8*)&As[cur][m * 32 + kk];
            const int n = wc * 64 + i * 16 + l15;
            b[i] = *(const short8*)&Bs[cur][n * 32 + kk];
        }
        __builtin_amdgcn_s_setprio(1);
#pragma unroll
        for (int i = 0; i < 4; i++)
#pragma unroll
            for (int j = 0; j < 4; j++)
                acc[i][j] = __builtin_amdgcn_mfma_f32_16x16x32_bf16(a[i], b[j], acc[i][j], 0, 0, 0);
        __builtin_amdgcn_s_setprio(0);
    }
#undef STAGE_B
#undef STAGE_A_GLDS
#undef STAGE_A_XFRM
#undef LOAD_H

    // epilogue: C/D layout col=lane&15, row=(lane>>4)*4+reg  [m89-verified]
    const int quad = lane >> 4;
    if (!ISB) {
        float bv[4];
#pragma unroll
        for (int j = 0; j < 4; j++)
            bv[j] = bias[dom * Ntot + n0 + wc * 64 + j * 16 + l15];
#pragma unroll
        for (int i = 0; i < 4; i++) {
#pragma unroll
            for (int r = 0; r < 4; r++) {
                const int rl = wr * 64 + i * 16 + quad * 4 + r;
                float s = 0.f, s2 = 0.f;
#pragma unroll
                for (int j = 0; j < 4; j++) {
                    const float v = acc[i][j][r] + bv[j];
                    Cbf[(size_t)(m0 + rl) * Ntot + n0 + wc * 64 + j * 16 + l15] = f2bf(v);
                    s += v; s2 += v * v;
                }
#pragma unroll
                for (int o = 8; o; o >>= 1) {
                    s  += __shfl_xor(s, o, 64);
                    s2 += __shfl_xor(s2, o, 64);
                }
                if (l15 == 0) {
                    atomicAdd(&sred[0][rl], s);    // LDS atomics: cheap
                    atomicAdd(&sred[1][rl], s2);
                }
            }
        }
        __syncthreads();
        if (tid < 128)
            spart[(size_t)(n0 >> 7) * MPAD + m0 + tid] =
                make_float2(sred[0][tid], sred[1][tid]);
    } else {
#pragma unroll
        for (int i = 0; i < 4; i++) {
            const int rowbase = m0 + wr * 64 + i * 16 + quad * 4;
#pragma unroll
            for (int r = 0; r < 4; r++) {
                const int orig = perm[rowbase + r];
                if (orig < 0) continue;     // padding row
#pragma unroll
                for (int j = 0; j < 4; j++) {
                    const int col = n0 + wc * 64 + j * 16 + l15;
                    Cf[(size_t)orig * Ntot + col] = acc[i][j][r] + bias[dom * Ntot + col];
                }
            }
        }
    }
}

// ---------------- launch ------------------------------------------------------
extern "C" void kernel_launch(void* const* d_in, const int* in_sizes, int n_in,
                              void* d_out, int out_size, void* d_ws, size_t ws_size,
                              hipStream_t stream) {
    const float* x = (const float*)d_in[0];
    const int* dt = (const int*)d_in[1];
    const float* W1 = (const float*)d_in[2];
    const float* b1 = (const float*)d_in[3];
    const float* gamma = (const float*)d_in[4];
    const float* beta = (const float*)d_in[5];
    const float* W2 = (const float*)d_in[6];
    const float* b2 = (const float*)d_in[7];
    float* out = (float*)d_out;

    char* ws = (char*)d_ws;
    size_t off = 0;
    auto take = [&](size_t nbytes) -> char* {
        char* p = ws + off;
        off = (off + nbytes + 255) & ~(size_t)255;
        return p;
    };
    unsigned short* W1T = (unsigned short*)take((size_t)ND * DHID * DIN * 2);   // [8,1024,256]
    unsigned short* W2T = (unsigned short*)take((size_t)ND * DOUT * DHID * 2);  // [8,256,1024]
    unsigned short* XS  = (unsigned short*)take((size_t)MPAD * DIN * 2);
    unsigned short* H   = (unsigned short*)take((size_t)MPAD * DHID * 2);
    float2* SPART = (float2*)take((size_t)8 * MPAD * 8);   // [8][MPAD] (s,s2)
    int* PERM   = (int*)take(MPAD * 4);
    int* POS    = (int*)take(NROWS * 4);
    int* CNT    = (int*)take(64);            // counts[8] then cursors[8]
    int2* META  = (int2*)take(NTILES * 8);
    (void)ws_size; (void)n_in; (void)in_sizes; (void)out_size;

    int* COUNTS = CNT;
    int* CURSORS = CNT + 8;

    transpose_both<<<4096, 256, 0, stream>>>(W1, W1T, W2, W2T, CNT);
    init_histo<<<MPAD / 256, 256, 0, stream>>>(dt, PERM, COUNTS);
    make_meta<<<1, 64, 0, stream>>>(COUNTS, CURSORS, META);
    assign_pos<<<NROWS / 256, 256, 0, stream>>>(dt, CURSORS, PERM, POS);
    copy_rows<<<NROWS / 4, 256, 0, stream>>>(x, POS, XS);
    gemm_bt<DIN, false><<<NTILES * 8, 256, 0, stream>>>(
        XS, W1T, b1, META, nullptr, H, nullptr, DHID, SPART, nullptr, nullptr);
    gemm_bt<DHID, true><<<NTILES * 2, 256, 0, stream>>>(
        H, W2T, b2, META, PERM, nullptr, out, DOUT, SPART, gamma, beta);
}